// Round 1
// baseline (1192.964 us; speedup 1.0000x reference)
//
#include <hip/hip_runtime.h>

// Problem constants (B=2, T=16, C=A=64, D=H=W=32)
#define NT 16
#define NC 64
#define NSP 32768            // D*H*W
#define NLOC 8               // w-tile per block; one wave per location
#define XS_STRIDE 1041       // 16*65 + 1 pad
#define MS_STRIDE 80         // 65 cols padded to 80 (cols >=65 are zero)
#define WV_STRIDE 66
#define ZP_STRIDE 257
#define FB_STRIDE 1025

__global__ __launch_bounds__(512)
void attn_fused_kernel(const float* __restrict__ x,
                       const float* __restrict__ Wk, const float* __restrict__ bk,
                       const float* __restrict__ Wq, const float* __restrict__ bq,
                       const float* __restrict__ Wv, const float* __restrict__ bv,
                       float* __restrict__ out) {
  // LDS: ~153.8 KB total -> 1 block/CU
  __shared__ float Xs[NLOC * XS_STRIDE];   // X~[loc][t][c], c<65 (col 64 == 1.0)
  __shared__ float Ys[NLOC * XS_STRIDE];   // Y[loc][t][cc]; reused as v[loc][t][c]
  __shared__ float Ms[65 * MS_STRIDE];     // M~[c][cc] (augmented), cols>=65 zero
  __shared__ float Wvs[65 * WV_STRIDE];    // W~v[c'][c] = Wv[c][c'], row 64 = bv
  __shared__ float Zb[NLOC * ZP_STRIDE];   // softmax denom over d, then 1/Z
  __shared__ float Pb[NLOC * ZP_STRIDE];   // P[loc][t*16+s] = exp(att)/Z
  __shared__ float Fb[NLOC * FB_STRIDE];   // feat transpose buffer [loc][s*64+c]

  const int tid = (int)threadIdx.x;
  const int bid = (int)blockIdx.x;
  const int w0  = (bid & 3) * NLOC;
  const int h   = (bid >> 2) & 31;
  const int b   = bid >> 7;
  const int spb = h * 32 + w0;                       // + d*1024 per slice
  const size_t xb = (size_t)b * 1024 * NSP;          // b*T*C*SP

  const int lane = tid & 63;
  const int loc  = tid >> 6;                         // wave id == location
  const int t0   = (lane >> 4) * 4;                  // 4-row group
  const int cb   = lane & 15;                        // col base

  const float scale = 0.125f;                        // 1/sqrt(64)

  // ---- per-block weight prep (redundant across blocks, trivial cost) ----
  // M~[c][cc]: c,cc<64: sum_a Wk[a,c]*Wq[a,cc]; M~[c][64]=sum_a Wk[a,c]*bq[a];
  // M~[64][cc]=sum_a bk[a]*Wq[a,cc]; M~[64][64]=bk.bq; cols 65..79 = 0.
  for (int o = tid; o < 65 * MS_STRIDE; o += 512) {
    int c = o / MS_STRIDE, cc = o % MS_STRIDE;
    float acc = 0.f;
    if (cc < 65) {
      if (c < 64 && cc < 64)      { for (int a = 0; a < 64; ++a) acc += Wk[a*64+c] * Wq[a*64+cc]; }
      else if (c < 64)            { for (int a = 0; a < 64; ++a) acc += Wk[a*64+c] * bq[a]; }
      else if (cc < 64)           { for (int a = 0; a < 64; ++a) acc += bk[a] * Wq[a*64+cc]; }
      else                        { for (int a = 0; a < 64; ++a) acc += bk[a] * bq[a]; }
    }
    Ms[o] = acc;
  }
  for (int o = tid; o < 65 * 64; o += 512) {
    int cp = o >> 6, c = o & 63;
    Wvs[cp * WV_STRIDE + c] = (cp < 64) ? Wv[c * 64 + cp] : bv[c];
  }
  for (int o = tid; o < NLOC * ZP_STRIDE; o += 512) Zb[o] = 0.f;

  const float* Xl = &Xs[loc * XS_STRIDE];
  float*       Yl = &Ys[loc * XS_STRIDE];

  // =================== PASS 1: accumulate Z over d ===================
  for (int d = 0; d < 32; ++d) {
    __syncthreads();                                  // protects Xs/Ys reuse
    // stage X~ for this d-slice (8 locations), coalesced over w
    const size_t gb = xb + (size_t)(d * 1024 + spb);
    for (int i = 0; i < 16; ++i) {
      int e = i * 512 + tid;
      int l = e & 7, tc = e >> 3;
      Xs[l * XS_STRIDE + (tc >> 6) * 65 + (tc & 63)] = x[gb + (size_t)tc * NSP + l];
    }
    if (tid < NLOC * NT)
      Xs[(tid >> 4) * XS_STRIDE + (tid & 15) * 65 + 64] = 1.f;
    __syncthreads();

    // Y = X~ @ M~  (each thread: 4 t-rows x 5 cc-cols)
    float acc[4][5];
    #pragma unroll
    for (int i = 0; i < 4; ++i)
      #pragma unroll
      for (int k = 0; k < 5; ++k) acc[i][k] = 0.f;
    for (int c = 0; c < 65; ++c) {
      float xv[4];
      #pragma unroll
      for (int i = 0; i < 4; ++i) xv[i] = Xl[(t0 + i) * 65 + c];
      #pragma unroll
      for (int k = 0; k < 5; ++k) {
        float m = Ms[c * MS_STRIDE + cb + 16 * k];    // zero for cc>=65
        #pragma unroll
        for (int i = 0; i < 4; ++i) acc[i][k] += xv[i] * m;
      }
    }
    #pragma unroll
    for (int k = 0; k < 5; ++k) {
      int cc = cb + 16 * k;
      if (cc < 65) {
        #pragma unroll
        for (int i = 0; i < 4; ++i) Yl[(t0 + i) * 65 + cc] = acc[i][k];
      }
    }
    __syncthreads();

    // att_raw[t][s] = sum_cc Y[t][cc] * X~[s][cc]; Z += exp(scale*att_raw)
    float accA[4] = {0.f, 0.f, 0.f, 0.f};
    for (int cc = 0; cc < 65; ++cc) {
      #pragma unroll
      for (int k = 0; k < 4; ++k) {
        int o = lane + 64 * k;
        accA[k] += Yl[(o >> 4) * 65 + cc] * Xl[(o & 15) * 65 + cc];
      }
    }
    #pragma unroll
    for (int k = 0; k < 4; ++k) {
      int o = lane + 64 * k;                          // o == t*16+s
      Zb[loc * ZP_STRIDE + o] += __expf(scale * accA[k]);
    }
  }

  __syncthreads();
  // invert Z once
  for (int o = tid; o < NLOC * 256; o += 512) {
    int l = o >> 8, r = o & 255;
    Zb[l * ZP_STRIDE + r] = 1.f / Zb[l * ZP_STRIDE + r];
  }

  // =================== PASS 2: recompute att, v, feat, write ===================
  for (int d = 0; d < 32; ++d) {
    __syncthreads();
    const size_t gb = xb + (size_t)(d * 1024 + spb);
    for (int i = 0; i < 16; ++i) {
      int e = i * 512 + tid;
      int l = e & 7, tc = e >> 3;
      Xs[l * XS_STRIDE + (tc >> 6) * 65 + (tc & 63)] = x[gb + (size_t)tc * NSP + l];
    }
    if (tid < NLOC * NT)
      Xs[(tid >> 4) * XS_STRIDE + (tid & 15) * 65 + 64] = 1.f;
    __syncthreads();

    // Y = X~ @ M~
    float acc[4][5];
    #pragma unroll
    for (int i = 0; i < 4; ++i)
      #pragma unroll
      for (int k = 0; k < 5; ++k) acc[i][k] = 0.f;
    for (int c = 0; c < 65; ++c) {
      float xv[4];
      #pragma unroll
      for (int i = 0; i < 4; ++i) xv[i] = Xl[(t0 + i) * 65 + c];
      #pragma unroll
      for (int k = 0; k < 5; ++k) {
        float m = Ms[c * MS_STRIDE + cb + 16 * k];
        #pragma unroll
        for (int i = 0; i < 4; ++i) acc[i][k] += xv[i] * m;
      }
    }
    #pragma unroll
    for (int k = 0; k < 5; ++k) {
      int cc = cb + 16 * k;
      if (cc < 65) {
        #pragma unroll
        for (int i = 0; i < 4; ++i) Yl[(t0 + i) * 65 + cc] = acc[i][k];
      }
    }
    __syncthreads();

    // P = exp(att)/Z
    float accA[4] = {0.f, 0.f, 0.f, 0.f};
    for (int cc = 0; cc < 65; ++cc) {
      #pragma unroll
      for (int k = 0; k < 4; ++k) {
        int o = lane + 64 * k;
        accA[k] += Yl[(o >> 4) * 65 + cc] * Xl[(o & 15) * 65 + cc];
      }
    }
    #pragma unroll
    for (int k = 0; k < 4; ++k) {
      int o = lane + 64 * k;
      Pb[loc * ZP_STRIDE + o] = __expf(scale * accA[k]) * Zb[loc * ZP_STRIDE + o];
    }

    // v = X~ @ W~v  (overwrites Ys; att reads of Ys are done in program order)
    float accV[4][4] = {};
    for (int cp = 0; cp < 65; ++cp) {
      float xv[4];
      #pragma unroll
      for (int i = 0; i < 4; ++i) xv[i] = Xl[(t0 + i) * 65 + cp];
      #pragma unroll
      for (int k = 0; k < 4; ++k) {
        float wv = Wvs[cp * WV_STRIDE + cb + 16 * k];
        #pragma unroll
        for (int i = 0; i < 4; ++i) accV[i][k] += xv[i] * wv;
      }
    }
    #pragma unroll
    for (int k = 0; k < 4; ++k)
      #pragma unroll
      for (int i = 0; i < 4; ++i) Yl[(t0 + i) * 65 + cb + 16 * k] = accV[i][k];
    __syncthreads();

    // feat[s][c] = sum_t v[t][c] * P[t][s]   (s group = t0, c = cb+16k)
    float accF[4][4] = {};
    for (int t = 0; t < NT; ++t) {
      float pv[4], vv[4];
      #pragma unroll
      for (int i = 0; i < 4; ++i) pv[i] = Pb[loc * ZP_STRIDE + t * 16 + t0 + i];
      #pragma unroll
      for (int k = 0; k < 4; ++k) vv[k] = Yl[t * 65 + cb + 16 * k];
      #pragma unroll
      for (int i = 0; i < 4; ++i)
        #pragma unroll
        for (int k = 0; k < 4; ++k) accF[i][k] += pv[i] * vv[k];
    }
    #pragma unroll
    for (int i = 0; i < 4; ++i)
      #pragma unroll
      for (int k = 0; k < 4; ++k)
        Fb[loc * FB_STRIDE + (t0 + i) * 64 + cb + 16 * k] = accF[i][k];
    __syncthreads();

    // cooperative write-out: out[b][s][c][d][h][w0+loc], w-contiguous
    const size_t ob = xb + (size_t)(d * 1024 + spb);
    for (int i = 0; i < 16; ++i) {
      int e = i * 512 + tid;
      int l = e & 7, sc = e >> 3;
      out[ob + (size_t)sc * NSP + l] = Fb[l * FB_STRIDE + sc];
    }
  }
}

extern "C" void kernel_launch(void* const* d_in, const int* in_sizes, int n_in,
                              void* d_out, int out_size, void* d_ws, size_t ws_size,
                              hipStream_t stream) {
  const float* x  = (const float*)d_in[0];
  const float* Wk = (const float*)d_in[1];
  const float* bk = (const float*)d_in[2];
  const float* Wq = (const float*)d_in[3];
  const float* bq = (const float*)d_in[4];
  const float* Wv = (const float*)d_in[5];
  const float* bv = (const float*)d_in[6];
  float* out = (float*)d_out;
  // grid = B * H * (W/NLOC) = 2*32*4 = 256 blocks, 512 threads (8 waves)
  attn_fused_kernel<<<256, 512, 0, stream>>>(x, Wk, bk, Wq, bq, Wv, bv, out);
}

// Round 2
// 341.903 us; speedup vs baseline: 3.4892x; 3.4892x over previous
//
#include <hip/hip_runtime.h>

typedef short v8s __attribute__((ext_vector_type(8)));
typedef float v4f __attribute__((ext_vector_type(4)));

#define NSP 32768

__device__ __forceinline__ unsigned short f2bf(float f) {
  union { float f; unsigned u; } v; v.f = f;
  unsigned r = v.u + 0x7fffu + ((v.u >> 16) & 1u);
  return (unsigned short)(r >> 16);
}
__device__ __forceinline__ unsigned pk(float a, float b) {
  return (unsigned)f2bf(a) | ((unsigned)f2bf(b) << 16);
}

union UF8 { v8s v; unsigned u[4]; uint4 q; };

// k-map guess used CONSISTENTLY for every A and B fragment (errors cancel):
// frag element j of lane (i16 + 16*g) <-> k = 16*(j>>2) + 4*g + (j&3)

// ---------------- prep kernel: weight fragments into ws ----------------
// ws dwords: frags f=0..17, each 64 lanes x 4 dwords (bf16 pairs). beta at dword 4608.
// f<8 : A-frags of M = Wk^T Wq   (tr = f>>1 rows 16tr+i16, kc = f&1)
// f=8,9: A-frags of [u; r; 0..]  (u = Wk^T bq, r = Wq^T bk), kc = f-8
// f>=10: B-frags of Wv^T for v-GEMM (tn = (f-10)>>1 cols, kc = (f-10)&1)
__global__ __launch_bounds__(512) void prep_kernel(
    const float* __restrict__ Wk, const float* __restrict__ bk,
    const float* __restrict__ Wq, const float* __restrict__ bq,
    const float* __restrict__ Wv, unsigned* __restrict__ ws) {
  __shared__ float sWk[4096], sWq[4096], sWv[4096], sbk[64], sbq[64];
  for (int i = threadIdx.x; i < 4096; i += 512) { sWk[i] = Wk[i]; sWq[i] = Wq[i]; sWv[i] = Wv[i]; }
  if (threadIdx.x < 64) { sbk[threadIdx.x] = bk[threadIdx.x]; sbq[threadIdx.x] = bq[threadIdx.x]; }
  __syncthreads();
  for (int task = threadIdx.x; task < 18 * 64; task += 512) {
    int f = task >> 6, lane = task & 63;
    int i16 = lane & 15, g = lane >> 4;
    unsigned short e[8];
    #pragma unroll
    for (int j = 0; j < 8; ++j) {
      int k = (((j >> 2) << 4) + 4 * g + (j & 3));
      float acc = 0.f;
      if (f < 8) {
        int row = ((f >> 1) << 4) + i16;            // c
        int cc  = ((f & 1) << 5) + k;               // cc
        for (int a = 0; a < 64; ++a) acc += sWk[a * 64 + row] * sWq[a * 64 + cc];
      } else if (f < 10) {
        int c = ((f - 8) << 5) + k;
        if (i16 == 0)      { for (int a = 0; a < 64; ++a) acc += sWk[a * 64 + c] * sbq[a]; }
        else if (i16 == 1) { for (int a = 0; a < 64; ++a) acc += sbk[a] * sWq[a * 64 + c]; }
      } else {
        int c  = (((f - 10) >> 1) << 4) + i16;      // out channel
        int cp = (((f - 10) & 1) << 5) + k;         // in channel
        acc = sWv[c * 64 + cp];
      }
      e[j] = f2bf(acc);
    }
    unsigned* dst = ws + (size_t)(f * 64 + lane) * 4;
    dst[0] = e[0] | ((unsigned)e[1] << 16);
    dst[1] = e[2] | ((unsigned)e[3] << 16);
    dst[2] = e[4] | ((unsigned)e[5] << 16);
    dst[3] = e[6] | ((unsigned)e[7] << 16);
  }
  if (threadIdx.x == 0) {
    float beta = 0.f;
    for (int a = 0; a < 64; ++a) beta += sbk[a] * sbq[a];
    ((float*)ws)[18 * 256] = beta;
  }
}

// ---------------- main fused kernel ----------------
// block <-> (b, h, w8-tile); wave <-> one w location; two d-passes (Z, then out).
__global__ __launch_bounds__(512, 2) void attn_main(
    const float* __restrict__ x, const float* __restrict__ bv,
    const unsigned* __restrict__ ws, float* __restrict__ out) {
  __shared__ __align__(16) unsigned char Xbuf[2][16512];  // 2 x 8 loc x (16x64 bf16, XOR-swizzled, loc stride 2064)
  __shared__ float Fb[8736];                              // out transpose: loc stride 1092, s stride 68

  const int tid = threadIdx.x;
  const int lane = tid & 63, wv = tid >> 6;
  const int i16 = lane & 15, g = lane >> 4;
  const int l8 = tid & 7, p0 = tid >> 3;

  // XCD line-pairing swizzle: consecutive L (w-halves of one 64B line) on same XCD
  int bid = (int)blockIdx.x;
  int L = ((bid & 7) << 5) | (bid >> 3);
  int w0 = (L & 3) << 3;
  int h  = (L >> 2) & 31;
  int b  = L >> 7;
  const int base0 = b * 33554432 + h * 32 + w0;   // + d*1024 + tc*NSP + w

  // constant weight fragments
  v8s fM[4][2], fUR[2], fWv[4][2];
  {
    const uint4* W4 = (const uint4*)ws;
    #pragma unroll
    for (int f = 0; f < 8; ++f) { UF8 u; u.q = W4[f * 64 + lane]; fM[f >> 1][f & 1] = u.v; }
    #pragma unroll
    for (int f = 0; f < 2; ++f) { UF8 u; u.q = W4[(8 + f) * 64 + lane]; fUR[f] = u.v; }
    #pragma unroll
    for (int f = 0; f < 8; ++f) { UF8 u; u.q = W4[(10 + f) * 64 + lane]; fWv[f >> 1][f & 1] = u.v; }
  }
  const float beta = ((const float*)ws)[4608];
  float bvv[4];
  #pragma unroll
  for (int tn = 0; tn < 4; ++tn) bvv[tn] = bv[i16 + 16 * tn];

  float sr0[8], sr1[8];
  auto issue = [&](int d) {
    const float* xp = x + base0 + d * 1024;
    #pragma unroll
    for (int i = 0; i < 8; ++i) {
      int tc = 2 * (p0 + 64 * i);
      sr0[i] = xp[(size_t)tc * NSP + l8];
      sr1[i] = xp[(size_t)(tc + 1) * NSP + l8];
    }
  };
  auto swrite = [&](int bb) {
    unsigned char* bp = &Xbuf[bb][l8 * 2064];
    #pragma unroll
    for (int i = 0; i < 8; ++i) {
      int tc = 2 * (p0 + 64 * i);
      int t = tc >> 6, c = tc & 63;
      int off = (t << 7) + (((c << 1)) ^ ((t & 7) << 4));
      *(unsigned*)(bp + off) = pk(sr0[i], sr1[i]);
    }
  };
  auto loadX = [&](int bb, v8s fX[2]) {
    const unsigned char* bp = &Xbuf[bb][wv * 2064 + (i16 << 7)];
    const int sw = (i16 & 7) << 4;
    #pragma unroll
    for (int kc = 0; kc < 2; ++kc) {
      union { v8s v; unsigned long long d[2]; } u;
      int o = (kc << 6) + (g << 3);
      u.d[0] = *(const unsigned long long*)(bp + (o ^ sw));
      u.d[1] = *(const unsigned long long*)(bp + ((o + 32) ^ sw));
      fX[kc] = u.v;
    }
  };
  // att(raw)[t=4g+j][s=i16] for this lane's 4 elements
  auto attOf = [&](const v8s fX[2]) -> v4f {
    v4f accW[4];
    #pragma unroll
    for (int tr = 0; tr < 4; ++tr) {
      v4f a = {0.f, 0.f, 0.f, 0.f};
      a = __builtin_amdgcn_mfma_f32_16x16x32_bf16(fM[tr][0], fX[0], a, 0, 0, 0);
      a = __builtin_amdgcn_mfma_f32_16x16x32_bf16(fM[tr][1], fX[1], a, 0, 0, 0);
      accW[tr] = a;   // W[16tr+4g+j][i16]
    }
    v4f au = {0.f, 0.f, 0.f, 0.f};
    au = __builtin_amdgcn_mfma_f32_16x16x32_bf16(fUR[0], fX[0], au, 0, 0, 0);
    au = __builtin_amdgcn_mfma_f32_16x16x32_bf16(fUR[1], fX[1], au, 0, 0, 0);
    float a1v = au[0] + beta;              // (Xu)[i16] + beta  (valid lanes 0..15)
    float a2v = au[1];                     // (Xr)[i16]
    float a2s = __shfl(a2v, i16);
    v4f att;
    #pragma unroll
    for (int j = 0; j < 4; ++j) att[j] = __shfl(a1v, 4 * g + j) + a2s;
    #pragma unroll
    for (int kc = 0; kc < 2; ++kc) {       // W D-regs chain directly into B-frags
      UF8 w;
      w.u[0] = pk(accW[2 * kc][0], accW[2 * kc][1]);
      w.u[1] = pk(accW[2 * kc][2], accW[2 * kc][3]);
      w.u[2] = pk(accW[2 * kc + 1][0], accW[2 * kc + 1][1]);
      w.u[3] = pk(accW[2 * kc + 1][2], accW[2 * kc + 1][3]);
      att = __builtin_amdgcn_mfma_f32_16x16x32_bf16(fX[kc], w.v, att, 0, 0, 0);
    }
    return att;
  };

  const float S2L = 0.18033688011112042f;  // (1/8) * log2(e)

  // =============== pass 1: Z (lane-local over d) ===============
  float Z[4] = {0.f, 0.f, 0.f, 0.f};
  issue(0); swrite(0);
  int cur = 0;
  for (int d = 0; d < 32; ++d) {
    __syncthreads();
    issue((d + 1) & 31);                  // d=31 pre-stages d=0 for pass 2
    v8s fX[2]; loadX(cur, fX);
    v4f att = attOf(fX);
    #pragma unroll
    for (int j = 0; j < 4; ++j) Z[j] += exp2f(att[j] * S2L);
    swrite(cur ^ 1);
    cur ^= 1;
  }
  float iZ[4];
  #pragma unroll
  for (int j = 0; j < 4; ++j) iZ[j] = 1.f / Z[j];

  // =============== pass 2: P, v, feat, write ===============
  for (int d = 0; d < 32; ++d) {
    __syncthreads();
    if (d < 31) issue(d + 1);
    v8s fX[2]; loadX(cur, fX);
    v4f att = attOf(fX);
    float p[4];
    #pragma unroll
    for (int j = 0; j < 4; ++j) p[j] = exp2f(att[j] * S2L) * iZ[j];
    v4f accV[4];
    #pragma unroll
    for (int tn = 0; tn < 4; ++tn) {
      v4f a = {bvv[tn], bvv[tn], bvv[tn], bvv[tn]};
      a = __builtin_amdgcn_mfma_f32_16x16x32_bf16(fX[0], fWv[tn][0], a, 0, 0, 0);
      a = __builtin_amdgcn_mfma_f32_16x16x32_bf16(fX[1], fWv[tn][1], a, 0, 0, 0);
      accV[tn] = a;   // v[4g+j][i16+16tn]
    }
    UF8 fP; fP.u[0] = pk(p[0], p[1]); fP.u[1] = pk(p[2], p[3]); fP.u[2] = 0; fP.u[3] = 0;
    #pragma unroll
    for (int tn = 0; tn < 4; ++tn) {
      UF8 fV; fV.u[0] = pk(accV[tn][0], accV[tn][1]); fV.u[1] = pk(accV[tn][2], accV[tn][3]);
      fV.u[2] = 0; fV.u[3] = 0;
      v4f ft = {0.f, 0.f, 0.f, 0.f};
      ft = __builtin_amdgcn_mfma_f32_16x16x32_bf16(fP.v, fV.v, ft, 0, 0, 0);  // feat[s=4g+j][c=i16+16tn]
      #pragma unroll
      for (int j = 0; j < 4; ++j)
        Fb[wv * 1092 + (4 * g + j) * 68 + i16 + 16 * tn] = ft[j];
    }
    if (d < 31) swrite(cur ^ 1);
    __syncthreads();
    float* op = out + base0 + d * 1024;
    #pragma unroll
    for (int i = 0; i < 16; ++i) {
      int e = i * 512 + tid;
      int le = e & 7, sc = e >> 3;
      op[(size_t)sc * NSP + le] = Fb[le * 1092 + ((sc >> 6) * 68) + (sc & 63)];
    }
    cur ^= 1;
  }
}

extern "C" void kernel_launch(void* const* d_in, const int* in_sizes, int n_in,
                              void* d_out, int out_size, void* d_ws, size_t ws_size,
                              hipStream_t stream) {
  const float* x  = (const float*)d_in[0];
  const float* Wk = (const float*)d_in[1];
  const float* bk = (const float*)d_in[2];
  const float* Wq = (const float*)d_in[3];
  const float* bq = (const float*)d_in[4];
  const float* Wv = (const float*)d_in[5];
  const float* bv = (const float*)d_in[6];
  float* out = (float*)d_out;
  unsigned* ws = (unsigned*)d_ws;

  prep_kernel<<<1, 512, 0, stream>>>(Wk, bk, Wq, bq, Wv, ws);
  attn_main<<<256, 512, 0, stream>>>(x, bv, ws, out);
}